// Round 15
// baseline (407.795 us; speedup 1.0000x reference)
//
#include <hip/hip_runtime.h>
#include <hip/hip_fp16.h>
#include <math.h>

// Problem constants (from reference): F_in=256, H=4, HID=64 -> D1=256, OUT=32
#define FIN  256
#define D1   256
#define NHEAD 4
#define HIDC 64
#define DOUT 32
#define NSLOPE 0.2f
#define SCHUNK 2048   // scan: elements per block (256 thr x 8)

typedef __attribute__((ext_vector_type(8))) short short8v;     // 8 bf16 bits
typedef __attribute__((ext_vector_type(8))) _Float16 half8v;   // 8 fp16
typedef __attribute__((ext_vector_type(4))) float f32x4;       // MFMA acc

__device__ __forceinline__ float lrelu(float x) { return x >= 0.f ? x : NSLOPE * x; }

// round-to-nearest-even fp32 -> bf16 split: x ~= hi + lo (both bf16)
__device__ __forceinline__ void bf16split(float x, unsigned short& h, unsigned short& l) {
  unsigned u = __float_as_uint(x);
  unsigned uh = (u + 0x7fffu + ((u >> 16) & 1u)) & 0xffff0000u;
  h = (unsigned short)(uh >> 16);
  float r = x - __uint_as_float(uh);
  unsigned ur = __float_as_uint(r);
  l = (unsigned short)((ur + 0x7fffu + ((ur >> 16) & 1u)) >> 16);
}

// ---------------- CSR construction ----------------
__global__ void zero2_kernel(int* __restrict__ a, int* __restrict__ b, int n) {
  int i = blockIdx.x * blockDim.x + threadIdx.x;
  if (i < n) { a[i] = 0; b[i] = 0; }
}

__global__ void count_kernel(const int* __restrict__ src, const int* __restrict__ dst,
                             int* __restrict__ deg, int E, int N) {
  int i = blockIdx.x * blockDim.x + threadIdx.x;
  if (i < E) {
    atomicAdd(&deg[dst[i]], 1);
  } else if (i < E + N) {
    atomicAdd(&deg[i - E], 1);   // self-loop
  }
}

// ---- hierarchical scan ----
__global__ __launch_bounds__(256) void scan1_kernel(const int* __restrict__ deg,
                                                    int* __restrict__ bsum, int N) {
  int b = blockIdx.x, t = threadIdx.x;
  int base = b * SCHUNK + t * 8;
  int s = 0;
  if (base + 8 <= N) {
    int4 a = *(const int4*)&deg[base];
    int4 c = *(const int4*)&deg[base + 4];
    s = a.x + a.y + a.z + a.w + c.x + c.y + c.z + c.w;
  } else {
#pragma unroll
    for (int i = 0; i < 8; ++i) if (base + i < N) s += deg[base + i];
  }
  int lane = t & 63, w = t >> 6;
#pragma unroll
  for (int off = 32; off >= 1; off >>= 1) s += __shfl_down(s, off);
  __shared__ int sh[4];
  if (lane == 0) sh[w] = s;
  __syncthreads();
  if (t == 0) bsum[b] = sh[0] + sh[1] + sh[2] + sh[3];
}

__global__ __launch_bounds__(1024) void scan2_kernel(int* __restrict__ bsum, int nb) {
  __shared__ int sh[1024];
  int t = threadIdx.x;
  sh[t] = (t < nb) ? bsum[t] : 0;
  __syncthreads();
  for (int off = 1; off < 1024; off <<= 1) {
    int u = (t >= off) ? sh[t - off] : 0;
    __syncthreads();
    sh[t] += u;
    __syncthreads();
  }
  if (t < nb) bsum[t] = sh[t];
}

__global__ __launch_bounds__(256) void scan3_kernel(const int* __restrict__ deg,
                                                    const int* __restrict__ bsum,
                                                    int* __restrict__ row_ptr, int N) {
  int b = blockIdx.x, t = threadIdx.x;
  int base = b * SCHUNK + t * 8;
  int vals[8];
  if (base + 8 <= N) {
    int4 a = *(const int4*)&deg[base];
    int4 c = *(const int4*)&deg[base + 4];
    vals[0] = a.x; vals[1] = a.y; vals[2] = a.z; vals[3] = a.w;
    vals[4] = c.x; vals[5] = c.y; vals[6] = c.z; vals[7] = c.w;
  } else {
#pragma unroll
    for (int i = 0; i < 8; ++i) vals[i] = (base + i < N) ? deg[base + i] : 0;
  }
  int s = 0;
#pragma unroll
  for (int i = 0; i < 8; ++i) { s += vals[i]; vals[i] = s; }
  int lane = t & 63, w = t >> 6;
  int inc = s;
#pragma unroll
  for (int off = 1; off < 64; off <<= 1) {
    int u = __shfl_up(inc, off);
    if (lane >= off) inc += u;
  }
  __shared__ int wsum[4];
  if (lane == 63) wsum[w] = inc;
  __syncthreads();
  int woff = 0;
#pragma unroll
  for (int i = 0; i < 4; ++i) if (i < w) woff += wsum[i];
  int excl = woff + inc - s;
  int offbase = (b ? bsum[b - 1] : 0) + excl;
#pragma unroll
  for (int i = 0; i < 8; ++i) {
    int idx = base + i;
    if (idx < N) row_ptr[idx + 1] = offbase + vals[i];
  }
  if (b == 0 && t == 0) row_ptr[0] = 0;
}

__global__ void scatter_kernel(const int* __restrict__ src, const int* __restrict__ dst,
                               const int* __restrict__ row_ptr, int* __restrict__ cur,
                               int* __restrict__ col, int E, int N) {
  int i = blockIdx.x * blockDim.x + threadIdx.x;
  int s, d;
  if (i < E) { s = src[i]; d = dst[i]; }
  else if (i < E + N) { s = i - E; d = i - E; }
  else return;
  int pos = row_ptr[d] + atomicAdd(&cur[d], 1);
  col[pos] = s;
}

// ---------------- weight prep: W1 split+transpose (bf16), W2 fp16 transpose ----------------
__global__ __launch_bounds__(256) void splitW1_kernel(const float* __restrict__ W1,
                                                      unsigned short* __restrict__ Wt_hi,
                                                      unsigned short* __restrict__ Wt_lo) {
  int t = blockIdx.x * 256 + threadIdx.x;   // 65536 threads
  int c = t >> 8, k = t & 255;
  float x = W1[(size_t)k * D1 + c];
  unsigned short h, l;
  bf16split(x, h, l);
  Wt_hi[(size_t)c * FIN + k] = h;
  Wt_lo[(size_t)c * FIN + k] = l;
}

__global__ __launch_bounds__(256) void splitW2_kernel(const float* __restrict__ W2,
                                                      __half* __restrict__ W2t) {
  int t = blockIdx.x * 256 + threadIdx.x;   // 8192 threads
  int c = t >> 8, k = t & 255;
  W2t[t] = __float2half(W2[(size_t)k * DOUT + c]);   // W2t[c][k]
}

// ---------------- GEMM1 (MFMA split-bf16): [N,256] @ [256,256] -> fp16 ----------------
// R14: B-frags read DIRECTLY from global (Wt is L2-resident); LDS holds only the
// A-tile (10 KB vs 50 KB) -> occupancy 3 -> ~6 blocks/CU, TLP hides latency.
__global__ __launch_bounds__(256) void gemm1_kernel(const float* __restrict__ A,
                                                    const unsigned short* __restrict__ Bt_hi,
                                                    const unsigned short* __restrict__ Bt_lo,
                                                    __half* __restrict__ C, int N) {
  __shared__ unsigned short As_hi[64][40];
  __shared__ unsigned short As_lo[64][40];
  int t = threadIdx.x;
  int row0 = blockIdx.x * 64;
  int lane = t & 63;
  int col0 = (t >> 6) * 64;
  int frow = lane & 15;
  int fk8  = lane >> 4;

  f32x4 acc[4][4];
#pragma unroll
  for (int i = 0; i < 4; ++i)
#pragma unroll
    for (int j = 0; j < 4; ++j)
#pragma unroll
      for (int q = 0; q < 4; ++q) acc[i][j][q] = 0.f;

  for (int k0 = 0; k0 < 256; k0 += 32) {
    // stage A: 64 rows x 32 k fp32 -> split bf16 hi/lo in LDS
    {
      int r = t >> 3;
      int kk = (t & 7) * 4;
#pragma unroll
      for (int rep = 0; rep < 2; ++rep) {
        int rr = r + rep * 32;
        int gr = row0 + rr;
        float4 v = {0.f, 0.f, 0.f, 0.f};
        if (gr < N) v = *(const float4*)&A[(size_t)gr * FIN + k0 + kk];
        unsigned short h0, l0, h1, l1, h2, l2, h3, l3;
        bf16split(v.x, h0, l0); bf16split(v.y, h1, l1);
        bf16split(v.z, h2, l2); bf16split(v.w, h3, l3);
        ushort4 vh = {h0, h1, h2, h3};
        ushort4 vl = {l0, l1, l2, l3};
        *(ushort4*)&As_hi[rr][kk] = vh;
        *(ushort4*)&As_lo[rr][kk] = vl;
      }
    }
    __syncthreads();
    // B frags straight from global (L2-hit): Bt[col][k], 4 fk8-lanes/col = 64B lines
    short8v bh[4], bl[4];
#pragma unroll
    for (int ct = 0; ct < 4; ++ct) {
      size_t bo = (size_t)(col0 + ct * 16 + frow) * FIN + k0 + fk8 * 8;
      bh[ct] = *(const short8v*)&Bt_hi[bo];
      bl[ct] = *(const short8v*)&Bt_lo[bo];
    }
#pragma unroll
    for (int rt = 0; rt < 4; ++rt) {
      short8v ah = *(const short8v*)&As_hi[rt * 16 + frow][fk8 * 8];
      short8v al = *(const short8v*)&As_lo[rt * 16 + frow][fk8 * 8];
#pragma unroll
      for (int ct = 0; ct < 4; ++ct) {
        acc[rt][ct] = __builtin_amdgcn_mfma_f32_16x16x32_bf16(ah, bh[ct], acc[rt][ct], 0, 0, 0);
        acc[rt][ct] = __builtin_amdgcn_mfma_f32_16x16x32_bf16(ah, bl[ct], acc[rt][ct], 0, 0, 0);
        acc[rt][ct] = __builtin_amdgcn_mfma_f32_16x16x32_bf16(al, bh[ct], acc[rt][ct], 0, 0, 0);
      }
    }
    __syncthreads();   // all waves done reading As before next overwrite
  }
#pragma unroll
  for (int rt = 0; rt < 4; ++rt) {
#pragma unroll
    for (int i = 0; i < 4; ++i) {
      int gr = row0 + rt * 16 + fk8 * 4 + i;
      if (gr < N) {
#pragma unroll
        for (int ct = 0; ct < 4; ++ct)
          C[(size_t)gr * D1 + col0 + ct * 16 + frow] = __float2half(acc[rt][ct][i]);
      }
    }
  }
}

// ---------------- alpha1: per-node dot with att vectors (fp16 h) ----------------
__global__ __launch_bounds__(256) void alpha1_kernel(const __half* __restrict__ h,
                                                     const float* __restrict__ a_src,
                                                     const float* __restrict__ a_dst,
                                                     float* __restrict__ as,
                                                     float* __restrict__ ad, int N) {
  int wid = (blockIdx.x * blockDim.x + threadIdx.x) >> 6;
  if (wid >= N) return;
  int lane = threadIdx.x & 63;
  int2 r = *(const int2*)&h[(size_t)wid * D1 + lane * 4];
  float2 f01 = __half22float2(*(__half2*)&r.x);
  float2 f23 = __half22float2(*(__half2*)&r.y);
  float4 s4 = *(const float4*)&a_src[lane * 4];
  float4 d4 = *(const float4*)&a_dst[lane * 4];
  float ps = f01.x * s4.x + f01.y * s4.y + f23.x * s4.z + f23.y * s4.w;
  float pd = f01.x * d4.x + f01.y * d4.y + f23.x * d4.z + f23.y * d4.w;
#pragma unroll
  for (int off = 8; off >= 1; off >>= 1) {
    ps += __shfl_xor(ps, off);
    pd += __shfl_xor(pd, off);
  }
  int hh = lane >> 4;
  if ((lane & 15) == 0) { as[wid * 4 + hh] = ps; ad[wid * 4 + hh] = pd; }
}

// ---------------- stats1: per-(node,head) stats + per-edge weights ----------------
__global__ __launch_bounds__(256) void stats1_kernel(const float* __restrict__ as1,
                                                     const float* __restrict__ ad1,
                                                     const int* __restrict__ row_ptr,
                                                     const int* __restrict__ col,
                                                     float* __restrict__ wbuf, int N) {
  int t = blockIdx.x * blockDim.x + threadIdx.x;
  if (t >= N * 4) return;
  int n = t >> 2, h = t & 3;
  int beg = row_ptr[n];
  int deg = row_ptr[n + 1] - beg;
  float adh = ad1[t];
  float m = -INFINITY, s = 0.f;
  int cn = col[beg];
  for (int j = 0; j < deg; ++j) {
    int c = cn;
    if (j + 1 < deg) cn = col[beg + j + 1];
    float e = lrelu(as1[(size_t)c * 4 + h] + adh);
    float nm = fmaxf(m, e);
    s = s * expf(m - nm) + expf(e - nm);
    m = nm;
  }
  float inv = 1.f / (s + 1e-16f);
  cn = col[beg];
  for (int j = 0; j < deg; ++j) {
    int c = cn;
    if (j + 1 < deg) cn = col[beg + j + 1];
    float e = lrelu(as1[(size_t)c * 4 + h] + adh);
    wbuf[(size_t)(beg + j) * 4 + h] = expf(e - m) * inv;
  }
}

// ---------------- agg1: weighted aggregate, fp16 gather + precomputed weights ----------------
__global__ __launch_bounds__(256) void agg1_kernel(const __half* __restrict__ hl,
                                                   const float* __restrict__ wbuf,
                                                   const int* __restrict__ row_ptr,
                                                   const int* __restrict__ col,
                                                   const float* __restrict__ b1,
                                                   __half* __restrict__ h1, int N) {
  int wid = (blockIdx.x * blockDim.x + threadIdx.x) >> 6;
  if (wid >= N) return;
  int lane = threadIdx.x & 63;
  int hm = lane >> 4;
  int beg = row_ptr[wid];
  int deg = row_ptr[wid + 1] - beg;
  float4 acc = {0.f, 0.f, 0.f, 0.f};
  int j = 0;
  for (; j + 4 <= deg; j += 4) {
    int s0 = col[beg + j + 0];
    int s1 = col[beg + j + 1];
    int s2 = col[beg + j + 2];
    int s3 = col[beg + j + 3];
    float w0 = wbuf[(size_t)(beg + j + 0) * 4 + hm];
    float w1 = wbuf[(size_t)(beg + j + 1) * 4 + hm];
    float w2 = wbuf[(size_t)(beg + j + 2) * 4 + hm];
    float w3 = wbuf[(size_t)(beg + j + 3) * 4 + hm];
    int2 r0 = *(const int2*)&hl[(size_t)s0 * D1 + lane * 4];
    int2 r1 = *(const int2*)&hl[(size_t)s1 * D1 + lane * 4];
    int2 r2 = *(const int2*)&hl[(size_t)s2 * D1 + lane * 4];
    int2 r3 = *(const int2*)&hl[(size_t)s3 * D1 + lane * 4];
    float2 u, v;
    u = __half22float2(*(__half2*)&r0.x); v = __half22float2(*(__half2*)&r0.y);
    acc.x = fmaf(w0, u.x, acc.x); acc.y = fmaf(w0, u.y, acc.y);
    acc.z = fmaf(w0, v.x, acc.z); acc.w = fmaf(w0, v.y, acc.w);
    u = __half22float2(*(__half2*)&r1.x); v = __half22float2(*(__half2*)&r1.y);
    acc.x = fmaf(w1, u.x, acc.x); acc.y = fmaf(w1, u.y, acc.y);
    acc.z = fmaf(w1, v.x, acc.z); acc.w = fmaf(w1, v.y, acc.w);
    u = __half22float2(*(__half2*)&r2.x); v = __half22float2(*(__half2*)&r2.y);
    acc.x = fmaf(w2, u.x, acc.x); acc.y = fmaf(w2, u.y, acc.y);
    acc.z = fmaf(w2, v.x, acc.z); acc.w = fmaf(w2, v.y, acc.w);
    u = __half22float2(*(__half2*)&r3.x); v = __half22float2(*(__half2*)&r3.y);
    acc.x = fmaf(w3, u.x, acc.x); acc.y = fmaf(w3, u.y, acc.y);
    acc.z = fmaf(w3, v.x, acc.z); acc.w = fmaf(w3, v.y, acc.w);
  }
  for (; j < deg; ++j) {
    int s0 = col[beg + j];
    float w0 = wbuf[(size_t)(beg + j) * 4 + hm];
    int2 r0 = *(const int2*)&hl[(size_t)s0 * D1 + lane * 4];
    float2 u = __half22float2(*(__half2*)&r0.x);
    float2 v = __half22float2(*(__half2*)&r0.y);
    acc.x = fmaf(w0, u.x, acc.x); acc.y = fmaf(w0, u.y, acc.y);
    acc.z = fmaf(w0, v.x, acc.z); acc.w = fmaf(w0, v.y, acc.w);
  }
  float4 bb = *(const float4*)&b1[lane * 4];
  __half2 p0 = __floats2half2_rn(fmaxf(acc.x + bb.x, 0.f), fmaxf(acc.y + bb.y, 0.f));
  __half2 p1 = __floats2half2_rn(fmaxf(acc.z + bb.z, 0.f), fmaxf(acc.w + bb.w, 0.f));
  int2 pk;
  pk.x = *(int*)&p0;
  pk.y = *(int*)&p1;
  *(int2*)&h1[(size_t)wid * D1 + lane * 4] = pk;
}

// ---------------- GEMM2 (MFMA f16): fp16 [N,256] @ [256,32] -> fp16 [N,32] ----------------
__global__ __launch_bounds__(256) void gemm2_kernel(const __half* __restrict__ A,
                                                    const __half* __restrict__ Bt,
                                                    __half* __restrict__ C, int N) {
  int t = threadIdx.x;
  int lane = t & 63;
  int frow = lane & 15, fk8 = lane >> 4;
  int row0 = (blockIdx.x * 4 + (t >> 6)) * 32;
  if (row0 >= N) return;
  half8v bf[8][2];
#pragma unroll
  for (int k8 = 0; k8 < 8; ++k8)
#pragma unroll
    for (int ct = 0; ct < 2; ++ct)
      bf[k8][ct] = *(const half8v*)&Bt[(size_t)(ct * 16 + frow) * 256 + k8 * 32 + fk8 * 8];
  f32x4 acc[2][2];
#pragma unroll
  for (int rt = 0; rt < 2; ++rt)
#pragma unroll
    for (int ct = 0; ct < 2; ++ct)
#pragma unroll
      for (int q = 0; q < 4; ++q) acc[rt][ct][q] = 0.f;
#pragma unroll
  for (int k8 = 0; k8 < 8; ++k8) {
#pragma unroll
    for (int rt = 0; rt < 2; ++rt) {
      int gr = row0 + rt * 16 + frow;
      if (gr >= N) gr = N - 1;                 // clamp; stores guarded
      half8v af = *(const half8v*)&A[(size_t)gr * D1 + k8 * 32 + fk8 * 8];
#pragma unroll
      for (int ct = 0; ct < 2; ++ct)
        acc[rt][ct] = __builtin_amdgcn_mfma_f32_16x16x32_f16(af, bf[k8][ct], acc[rt][ct], 0, 0, 0);
    }
  }
#pragma unroll
  for (int rt = 0; rt < 2; ++rt)
#pragma unroll
    for (int i = 0; i < 4; ++i) {
      int gr = row0 + rt * 16 + fk8 * 4 + i;
      if (gr < N) {
#pragma unroll
        for (int ct = 0; ct < 2; ++ct)
          C[(size_t)gr * DOUT + ct * 16 + frow] = __float2half(acc[rt][ct][i]);
      }
    }
}

// ---------------- alpha2: one wave handles two nodes (fp16 h2) ----------------
__global__ __launch_bounds__(256) void alpha2_kernel(const __half* __restrict__ h2,
                                                     const float* __restrict__ a_src,
                                                     const float* __restrict__ a_dst,
                                                     float* __restrict__ as,
                                                     float* __restrict__ ad, int N) {
  int wid = (blockIdx.x * blockDim.x + threadIdx.x) >> 6;
  int lane = threadIdx.x & 63;
  int n = wid * 2 + (lane >> 5);
  int c = lane & 31;
  float v = (n < N) ? __half2float(h2[(size_t)n * DOUT + c]) : 0.f;
  float ps = v * a_src[c];
  float pd = v * a_dst[c];
#pragma unroll
  for (int off = 16; off >= 1; off >>= 1) {
    ps += __shfl_xor(ps, off);
    pd += __shfl_xor(pd, off);
  }
  if (c == 0 && n < N) { as[n] = ps; ad[n] = pd; }
}

// ---------------- stats2: per-node stats + per-edge weights (H=1) ----------------
__global__ __launch_bounds__(256) void stats2_kernel(const float* __restrict__ as2,
                                                     const float* __restrict__ ad2,
                                                     const int* __restrict__ row_ptr,
                                                     const int* __restrict__ col,
                                                     float* __restrict__ wbuf2, int N) {
  int n = blockIdx.x * blockDim.x + threadIdx.x;
  if (n >= N) return;
  int beg = row_ptr[n];
  int deg = row_ptr[n + 1] - beg;
  float ad = ad2[n];
  float m = -INFINITY, s = 0.f;
  int cn = col[beg];
  for (int j = 0; j < deg; ++j) {
    int c = cn;
    if (j + 1 < deg) cn = col[beg + j + 1];
    float e = lrelu(as2[c] + ad);
    float nm = fmaxf(m, e);
    s = s * expf(m - nm) + expf(e - nm);
    m = nm;
  }
  float inv = 1.f / (s + 1e-16f);
  cn = col[beg];
  for (int j = 0; j < deg; ++j) {
    int c = cn;
    if (j + 1 < deg) cn = col[beg + j + 1];
    wbuf2[beg + j] = expf(lrelu(as2[c] + ad) - m) * inv;
  }
}

// ---------------- agg2: weighted aggregate (H=1, C=32), precomputed weights ----------------
__global__ __launch_bounds__(256) void agg2_kernel(const __half* __restrict__ h2,
                                                   const float* __restrict__ wbuf2,
                                                   const int* __restrict__ row_ptr,
                                                   const int* __restrict__ col,
                                                   const float* __restrict__ b2,
                                                   float* __restrict__ out, int N) {
  int wid = (blockIdx.x * blockDim.x + threadIdx.x) >> 6;
  if (wid >= N) return;
  int lane = threadIdx.x & 63;
  int c = lane & 31;
  int beg = row_ptr[wid];
  int deg = row_ptr[wid + 1] - beg;
  float acc = 0.f;
  int j = 0;
  for (; j + 4 <= deg; j += 4) {
    int s0 = col[beg + j + 0];
    int s1 = col[beg + j + 1];
    int s2 = col[beg + j + 2];
    int s3 = col[beg + j + 3];
    float w0 = wbuf2[beg + j + 0];
    float w1 = wbuf2[beg + j + 1];
    float w2 = wbuf2[beg + j + 2];
    float w3 = wbuf2[beg + j + 3];
    float v0 = __half2float(h2[(size_t)s0 * DOUT + c]);
    float v1 = __half2float(h2[(size_t)s1 * DOUT + c]);
    float v2 = __half2float(h2[(size_t)s2 * DOUT + c]);
    float v3 = __half2float(h2[(size_t)s3 * DOUT + c]);
    acc = fmaf(w0, v0, acc);
    acc = fmaf(w1, v1, acc);
    acc = fmaf(w2, v2, acc);
    acc = fmaf(w3, v3, acc);
  }
  for (; j < deg; ++j) {
    int s0 = col[beg + j];
    float w0 = wbuf2[beg + j];
    acc = fmaf(w0, __half2float(h2[(size_t)s0 * DOUT + c]), acc);
  }
  if (lane < 32) out[(size_t)wid * DOUT + c] = acc + b2[c];
}

// ---------------- launch ----------------
extern "C" void kernel_launch(void* const* d_in, const int* in_sizes, int n_in,
                              void* d_out, int out_size, void* d_ws, size_t ws_size,
                              hipStream_t stream) {
  const float* x     = (const float*)d_in[0];
  const int*   ei    = (const int*)d_in[1];
  const float* W1    = (const float*)d_in[2];
  const float* asrc1 = (const float*)d_in[3];
  const float* adst1 = (const float*)d_in[4];
  const float* b1    = (const float*)d_in[5];
  const float* W2    = (const float*)d_in[6];
  const float* asrc2 = (const float*)d_in[7];
  const float* adst2 = (const float*)d_in[8];
  const float* b2    = (const float*)d_in[9];

  const int N = in_sizes[0] / FIN;
  const int E = in_sizes[1] / 2;
  const int ET = E + N;
  const int* src = ei;
  const int* dst = ei + E;
  const int NB = (N + SCHUNK - 1) / SCHUNK;

  char* base = (char*)d_ws;
  size_t off = 0;
  auto alloc = [&](size_t bytes) -> void* {
    void* p = base + off;
    off = (off + bytes + 255) & ~(size_t)255;
    return p;
  };
  int* row_ptr = (int*)alloc((size_t)(N + 1) * 4);
  int* deg     = (int*)alloc((size_t)N * 4);
  int* cur     = (int*)alloc((size_t)N * 4);
  int* col     = (int*)alloc((size_t)ET * 4);
  int* bsum    = (int*)alloc((size_t)1024 * 4);
  float* as1   = (float*)alloc((size_t)N * 4 * 4);
  float* ad1   = (float*)alloc((size_t)N * 4 * 4);
  float* as2   = (float*)alloc((size_t)N * 4);
  float* ad2   = (float*)alloc((size_t)N * 4);
  float* wbuf1 = (float*)alloc((size_t)ET * 4 * 4);
  float* wbuf2 = (float*)alloc((size_t)ET * 4);
  unsigned short* Wt_hi = (unsigned short*)alloc((size_t)FIN * D1 * 2);
  unsigned short* Wt_lo = (unsigned short*)alloc((size_t)FIN * D1 * 2);
  __half* W2t  = (__half*)alloc((size_t)D1 * DOUT * 2);
  __half* hl1  = (__half*)alloc((size_t)N * D1 * 2);   // fp16 gather source L1
  __half* h1   = (__half*)alloc((size_t)N * D1 * 2);   // fp16, streamed by gemm2
  __half* h2   = hl1;   // reuse: hl1 dead after agg1
  float* out   = (float*)d_out;

  // CSR build + weight prep
  hipLaunchKernelGGL(zero2_kernel, dim3((N + 255) / 256), dim3(256), 0, stream, deg, cur, N);
  hipLaunchKernelGGL(count_kernel, dim3((ET + 255) / 256), dim3(256), 0, stream, src, dst, deg, E, N);
  hipLaunchKernelGGL(splitW1_kernel, dim3(FIN * D1 / 256), dim3(256), 0, stream, W1, Wt_hi, Wt_lo);
  hipLaunchKernelGGL(splitW2_kernel, dim3(D1 * DOUT / 256), dim3(256), 0, stream, W2, W2t);
  hipLaunchKernelGGL(scan1_kernel, dim3(NB), dim3(256), 0, stream, deg, bsum, N);
  hipLaunchKernelGGL(scan2_kernel, dim3(1), dim3(1024), 0, stream, bsum, NB);
  hipLaunchKernelGGL(scan3_kernel, dim3(NB), dim3(256), 0, stream, deg, bsum, row_ptr, N);
  hipLaunchKernelGGL(scatter_kernel, dim3((ET + 255) / 256), dim3(256), 0, stream, src, dst, row_ptr, cur, col, E, N);

  // layer 1
  hipLaunchKernelGGL(gemm1_kernel, dim3((N + 63) / 64), dim3(256), 0, stream, x, Wt_hi, Wt_lo, hl1, N);
  hipLaunchKernelGGL(alpha1_kernel, dim3((N + 3) / 4), dim3(256), 0, stream, hl1, asrc1, adst1, as1, ad1, N);
  hipLaunchKernelGGL(stats1_kernel, dim3((N * 4 + 255) / 256), dim3(256), 0, stream, as1, ad1, row_ptr, col, wbuf1, N);
  hipLaunchKernelGGL(agg1_kernel, dim3((N + 3) / 4), dim3(256), 0, stream, hl1, wbuf1, row_ptr, col, b1, h1, N);

  // layer 2
  hipLaunchKernelGGL(gemm2_kernel, dim3((N / 32 + 4) / 4), dim3(256), 0, stream, h1, W2t, h2, N);
  hipLaunchKernelGGL(alpha2_kernel, dim3((N + 7) / 8), dim3(256), 0, stream, h2, asrc2, adst2, as2, ad2, N);
  hipLaunchKernelGGL(stats2_kernel, dim3((N + 255) / 256), dim3(256), 0, stream, as2, ad2, row_ptr, col, wbuf2, N);
  hipLaunchKernelGGL(agg2_kernel, dim3((N + 3) / 4), dim3(256), 0, stream, h2, wbuf2, row_ptr, col, b2, out, N);
}